// Round 20
// baseline (297.244 us; speedup 1.0000x reference)
//
#include <hip/hip_runtime.h>
#include <hip/hip_bf16.h>
#include <math.h>

typedef unsigned short u16;
typedef __attribute__((ext_vector_type(8))) short bf8_t;
typedef __attribute__((ext_vector_type(8))) unsigned short us8_t;
typedef __attribute__((ext_vector_type(4))) float f4_t;

#define BB 16
#define CC 768
#define HH 32
#define WW 32
#define HWL 1024
#define NHH 12
#define HDD 64
#define HK 16
#define NS 256
#define RT 31

__device__ inline float us2f(u16 u) {
    return __uint_as_float(((unsigned int)u) << 16);
}
__device__ inline u16 f2us(float f) {
    unsigned int u = __float_as_uint(f);
    unsigned int r = (u + 0x7fffu + ((u >> 16) & 1u)) >> 16;
    return (u16)r;
}

// -------------------- K1: all four depthwise convs (4 px/thread) -------------
__global__ __launch_bounds__(256) void k_dwconv(
    const float* __restrict__ x,
    const float* __restrict__ wv, const float* __restrict__ bv,
    const float* __restrict__ wq, const float* __restrict__ bq,
    const float* __restrict__ wk, const float* __restrict__ bk,
    const float* __restrict__ wo, const float* __restrict__ bo,
    u16* __restrict__ value, u16* __restrict__ query,
    u16* __restrict__ key, float* __restrict__ tbuf)
{
    __shared__ float xs[34 * 34];
    int blk = blockIdx.x;
    int b = blk / CC, c = blk % CC;
    int tid = threadIdx.x;
    const float* xp = x + (size_t)(b * CC + c) * HWL;

    for (int i = tid; i < 34 * 34; i += 256) {
        int r = i / 34, cc2 = i % 34;
        int gr = r - 1, gc = cc2 - 1;
        float v = 0.f;
        if (gr >= 0 && gr < 32 && gc >= 0 && gc < 32) v = xp[gr * 32 + gc];
        xs[i] = v;
    }
    float wv_[9], wq_[9], wk_[9], wo_[9];
#pragma unroll
    for (int k = 0; k < 9; ++k) {
        wv_[k] = wv[c * 9 + k];
        wq_[k] = wq[c * 9 + k];
        wk_[k] = wk[c * 9 + k];
        wo_[k] = wo[c * 9 + k];
    }
    float bv_ = bv[c], bq_ = bq[c], bk_ = bk[c], bo_ = bo[c];
    __syncthreads();

    // stride-1: 4 consecutive px per thread; 3x6 window loaded once (18 ds_reads)
    {
        int oy = tid >> 3;            // 0..31
        int ox4 = (tid & 7) * 4;      // 0,4,...,28
        float xw[3][6];
#pragma unroll
        for (int dy = 0; dy < 3; ++dy)
#pragma unroll
            for (int dx = 0; dx < 6; ++dx)
                xw[dy][dx] = xs[(oy + dy) * 34 + ox4 + dx];
        union { u16 u[4]; ushort4 v; } pv, pq;
#pragma unroll
        for (int j = 0; j < 4; ++j) {
            float av = 0.f, aq = 0.f;
#pragma unroll
            for (int dy = 0; dy < 3; ++dy)
#pragma unroll
                for (int dx = 0; dx < 3; ++dx) {
                    float xv = xw[dy][j + dx];
                    av += xv * wv_[dy * 3 + dx];
                    aq += xv * wq_[dy * 3 + dx];
                }
            pv.u[j] = f2us(av + bv_);
            pq.u[j] = f2us(aq + bq_);
        }
        size_t o = (size_t)(b * CC + c) * HWL + oy * 32 + ox4;
        *(ushort4*)&value[o] = pv.v;
        *(ushort4*)&query[o] = pq.v;
    }
    // stride-2: key (bf16 [b][c][n]), offset-pre t (f32 [b][c][n], coalesced)
    {
        int oy = tid >> 4, ox = tid & 15;
        float ak = 0.f, ao2 = 0.f;
#pragma unroll
        for (int dy = 0; dy < 3; ++dy)
#pragma unroll
            for (int dx = 0; dx < 3; ++dx) {
                float xv = xs[(2 * oy + dy) * 34 + 2 * ox + dx];
                ak += xv * wk_[dy * 3 + dx];
                ao2 += xv * wo_[dy * 3 + dx];
            }
        key[(size_t)(b * CC + c) * NS + tid] = f2us(ak + bk_);
        tbuf[(size_t)(b * CC + c) * NS + tid] = ao2 + bo_;
    }
}

// -------------------- K2: LN + GELU + 1x1 -> offsets -> pos --------------------
__global__ __launch_bounds__(256) void k_offset(
    const float* __restrict__ tbuf,
    const float* __restrict__ lng, const float* __restrict__ lnb,
    const float* __restrict__ woff2, float* __restrict__ pos)
{
    __shared__ float sm[16];
    int blk = blockIdx.x;
    int b = blk >> 8;
    int n = blk & 255;
    int tid = threadIdx.x;
    const float* tp = tbuf + (size_t)b * CC * NS + n;
    float tv0 = tp[(size_t)tid * NS];
    float tv1 = tp[(size_t)(tid + 256) * NS];
    float tv2 = tp[(size_t)(tid + 512) * NS];
    float s = tv0 + tv1 + tv2;
    float sq = tv0 * tv0 + tv1 * tv1 + tv2 * tv2;
    for (int o = 32; o; o >>= 1) { s += __shfl_down(s, o); sq += __shfl_down(sq, o); }
    int w = tid >> 6;
    if ((tid & 63) == 0) { sm[w] = s; sm[4 + w] = sq; }
    __syncthreads();
    float st = sm[0] + sm[1] + sm[2] + sm[3];
    float sqt = sm[4] + sm[5] + sm[6] + sm[7];
    float mean = st * (1.f / 768.f);
    float var = sqt * (1.f / 768.f) - mean * mean;
    float rstd = rsqrtf(fmaxf(var, 0.f) + 1e-5f);

    float oy = 0.f, ox = 0.f;
#pragma unroll
    for (int j = 0; j < 3; ++j) {
        int c = tid + j * 256;
        float tvj = (j == 0) ? tv0 : ((j == 1) ? tv1 : tv2);
        float xn = (tvj - mean) * rstd;
        float y = xn * lng[c] + lnb[c];
        float ge = 0.5f * y * (1.f + erff(y * 0.70710678118654752f));
        oy += ge * woff2[c];
        ox += ge * woff2[CC + c];
    }
    for (int o = 32; o; o >>= 1) { oy += __shfl_down(oy, o); ox += __shfl_down(ox, o); }
    __syncthreads();
    if ((tid & 63) == 0) { sm[w] = oy; sm[8 + w] = ox; }
    __syncthreads();
    if (tid == 0) {
        float oyt = sm[0] + sm[1] + sm[2] + sm[3];
        float oxt = sm[8] + sm[9] + sm[10] + sm[11];
        float offy = tanhf(oyt) * 0.125f;
        float offx = tanhf(oxt) * 0.125f;
        int ky = n >> 4, kx = n & 15;
        pos[blk * 2 + 0] = (ky + 0.5f) * 0.125f - 1.f + offy;
        pos[blk * 2 + 1] = (kx + 0.5f) * 0.125f - 1.f + offx;
    }
}

// -------------------- K3: sample value at pos -> vst [b][c][n] directly ------
__global__ __launch_bounds__(256) void k_sample(
    const u16* __restrict__ value, const float* __restrict__ pos,
    u16* __restrict__ vst)
{
    __shared__ float psl[NS * 2];
    int cg = blockIdx.x;
    int b  = blockIdx.y;
    int tid = threadIdx.x;
    for (int i = tid; i < NS * 2; i += 256) psl[i] = pos[b * NS * 2 + i];
    __syncthreads();
    int c = cg * 4 + (tid >> 6);
    int nl = tid & 63;
    const u16* vp = value + (size_t)(b * CC + c) * HWL;
    u16* op = vst + (size_t)(b * CC + c) * NS;
#pragma unroll
    for (int j = 0; j < 4; ++j) {
        int n = j * 64 + nl;
        float py = psl[2 * n], px = psl[2 * n + 1];
        float gx = (px + 1.f) * 15.5f;
        float gy = (py + 1.f) * 15.5f;
        float fx = floorf(gx), fy = floorf(gy);
        float wx = gx - fx, wy = gy - fy;
        int ix0 = (int)fx, iy0 = (int)fy;
        int ix1 = ix0 + 1, iy1 = iy0 + 1;
        float m00 = ((unsigned)ix0 < 32u && (unsigned)iy0 < 32u) ? 1.f : 0.f;
        float m01 = ((unsigned)ix1 < 32u && (unsigned)iy0 < 32u) ? 1.f : 0.f;
        float m10 = ((unsigned)ix0 < 32u && (unsigned)iy1 < 32u) ? 1.f : 0.f;
        float m11 = ((unsigned)ix1 < 32u && (unsigned)iy1 < 32u) ? 1.f : 0.f;
        int cx0 = min(max(ix0, 0), 31), cx1 = min(max(ix1, 0), 31);
        int cy0 = min(max(iy0, 0), 31), cy1 = min(max(iy1, 0), 31);
        float w00 = (1.f - wy) * (1.f - wx) * m00;
        float w01 = (1.f - wy) * wx * m01;
        float w10 = wy * (1.f - wx) * m10;
        float w11 = wy * wx * m11;
        float r = w00 * us2f(vp[cy0 * 32 + cx0]) + w01 * us2f(vp[cy0 * 32 + cx1])
                + w10 * us2f(vp[cy1 * 32 + cx0]) + w11 * us2f(vp[cy1 * 32 + cx1]);
        op[n] = f2us(r);
    }
}

// -------------------- K3b: batched 64x64 bf16 transpose (key -> kt) ----------
__global__ __launch_bounds__(256) void k_transpose(
    const u16* __restrict__ in, u16* __restrict__ out, int R, int S)
{
    __shared__ u16 tile[64][68];
    int bx = blockIdx.x;
    int by = blockIdx.y;
    int bz = blockIdx.z;
    int t = threadIdx.x;
    int ci = (t & 15) * 4;
    int ri = t >> 4;
    const u16* ip = in + (size_t)bz * R * S;
    u16* op = out + (size_t)bz * R * S;
#pragma unroll
    for (int i = 0; i < 4; ++i) {
        int r = ri + i * 16;
        ushort4 v = *(const ushort4*)(ip + (size_t)(by * 64 + r) * S + bx * 64 + ci);
        *(ushort4*)&tile[r][ci] = v;
    }
    __syncthreads();
#pragma unroll
    for (int i = 0; i < 4; ++i) {
        int s = ri + i * 16;
        ushort4 v;
        v.x = tile[ci + 0][s];
        v.y = tile[ci + 1][s];
        v.z = tile[ci + 2][s];
        v.w = tile[ci + 3][s];
        *(ushort4*)(op + (size_t)(bx * 64 + s) * R + by * 64 + ci) = v;
    }
}

// -------------------- K3c: wout f32 -> bf16 ----------------------------------
__global__ __launch_bounds__(256) void k_cvtw(
    const float* __restrict__ w, u16* __restrict__ wbf)
{
    int i = (blockIdx.x * 256 + threadIdx.x) * 4;
    float4 v = *(const float4*)(w + i);
    union { u16 u[4]; ushort4 v; } pk;
    pk.u[0] = f2us(v.x); pk.u[1] = f2us(v.y);
    pk.u[2] = f2us(v.z); pk.u[3] = f2us(v.w);
    *(ushort4*)(wbf + i) = pk.v;
}

// -------------------- K4: MFMA fused attention (r18 — LDS-staged K/V) --------
__global__ __launch_bounds__(256, 4) void k_attn(
    const u16* __restrict__ query, const u16* __restrict__ kt,
    const u16* __restrict__ vst, const float* __restrict__ rpe,
    const float* __restrict__ pos, u16* __restrict__ ao)
{
    __shared__ float2 tabp2[35 * 36];  // .x=tab[r][c], .y=tab[r][c+1] (padded +2)
    __shared__ float2 psl2[NS];
    __shared__ u16 Plds[4][16][72];
    __shared__ u16 KsS[4096];          // 64 rows x 64 bf16, XOR-swizzled
    __shared__ u16 VsS[4096];

    int L = blockIdx.x;
    int xcd = L & 7;
    int t2 = L >> 3;
    int mt = t2 & 15;          // m tile of 64
    int bh = xcd + 8 * (t2 >> 4);
    int b = bh / NHH, h = bh % NHH;
    int tid = threadIdx.x;
    int w = tid >> 6;
    int l = tid & 63;
    int li = l & 15, lg4 = l >> 4;

    for (int i = tid; i < 35 * 36; i += 256) {
        int r = i / 36, c = i % 36;
        int rr = r - 2;
        int c0i = c - 2, c1i = c - 1;
        float v0 = ((unsigned)rr < 31u && (unsigned)c0i < 31u)
                       ? rpe[h * RT * RT + rr * RT + c0i] : 0.f;
        float v1 = ((unsigned)rr < 31u && (unsigned)c1i < 31u)
                       ? rpe[h * RT * RT + rr * RT + c1i] : 0.f;
        tabp2[i] = make_float2(v0, v1);
    }
    for (int i = tid; i < NS; i += 256) {
        psl2[i] = make_float2(pos[b * NS * 2 + 2 * i], pos[b * NS * 2 + 2 * i + 1]);
    }

    int c0 = h * 64;

    // prologue: stage chunk 0 K/V (reg-staged, swizzled write)
#pragma unroll
    for (int it = 0; it < 2; ++it) {
        int Li = tid + it * 256;          // 0..511
        int row = Li >> 3;                // 0..63
        int colb = (Li & 7) * 16;         // byte col within 128B row
        us8_t kv = *(const us8_t*)(kt  + (size_t)(b * NS + row) * CC + c0 + colb / 2);
        us8_t vv = *(const us8_t*)(vst + (size_t)(b * CC + c0 + row) * NS + colb / 2);
        int so = (Li * 16) ^ ((row & 7) << 4);
        *(us8_t*)((char*)KsS + so) = kv;
        *(us8_t*)((char*)VsS + so) = vv;
    }
    __syncthreads();

    int m0 = mt * 64 + w * 16;

    // Q fragments directly from query [b][c][m]: row=li(m), k=c
    bf8_t qf[2];
#pragma unroll
    for (int ks = 0; ks < 2; ++ks) {
        union { short s[8]; bf8_t v; } u;
#pragma unroll
        for (int j = 0; j < 8; ++j)
            u.s[j] = (short)query[(size_t)(b * CC + c0 + ks * 32 + lg4 * 8 + j) * HWL + m0 + li];
        qf[ks] = u.v;
    }
    // all-ones B fragment (bf16 1.0) for MFMA row-sum
    bf8_t ones;
    {
        union { short s[8]; bf8_t v; } u;
#pragma unroll
        for (int j = 0; j < 8; ++j) u.s[j] = (short)0x3F80;
        ones = u.v;
    }

    f4_t O[4];
#pragma unroll
    for (int ci = 0; ci < 4; ++ci) O[ci] = (f4_t){0.f, 0.f, 0.f, 0.f};
    float mrun[4], lrun[4];
#pragma unroll
    for (int r = 0; r < 4; ++r) { mrun[r] = -1e30f; lrun[r] = 0.f; }

    int mrow = m0 + lg4 * 4;
    float qgy  = ((mrow >> 5) + 0.5f) * 0.0625f - 1.f;
    float qgx0 = ((mrow & 31) + 0.5f) * 0.0625f - 1.f;

    for (int chunk = 0; chunk < 4; ++chunk) {
        int n0 = chunk * 64;

        // K fragments from LDS (swizzled read, 2-way free)
        bf8_t kf[4][2];
#pragma unroll
        for (int ni = 0; ni < 4; ++ni)
#pragma unroll
            for (int ks = 0; ks < 2; ++ks) {
                int addr = (ni * 16 + li) * 128 + ks * 64 + lg4 * 16;
                kf[ni][ks] = *(const bf8_t*)((const char*)KsS + (addr ^ ((li & 7) << 4)));
            }

        // T14: issue next chunk's global loads early (latency hides under compute)
        us8_t nk[2], nv[2];
        if (chunk < 3) {
            int n1 = n0 + 64;
#pragma unroll
            for (int it = 0; it < 2; ++it) {
                int Li = tid + it * 256;
                int row = Li >> 3;
                int colb = (Li & 7) * 16;
                nk[it] = *(const us8_t*)(kt  + (size_t)(b * NS + n1 + row) * CC + c0 + colb / 2);
                nv[it] = *(const us8_t*)(vst + (size_t)(b * CC + c0 + row) * NS + n1 + colb / 2);
            }
        }

        f4_t s[4];
#pragma unroll
        for (int ni = 0; ni < 4; ++ni) {
            f4_t acc = (f4_t){0.f, 0.f, 0.f, 0.f};
            acc = __builtin_amdgcn_mfma_f32_16x16x32_bf16(qf[0], kf[ni][0], acc, 0, 0, 0);
            acc = __builtin_amdgcn_mfma_f32_16x16x32_bf16(qf[1], kf[ni][1], acc, 0, 0, 0);
            s[ni] = acc;
        }

        // scale + RPE bias (C-layout: col n = li, row m = lg4*4+r)
#pragma unroll
        for (int ni = 0; ni < 4; ++ni) {
            int n = n0 + ni * 16 + li;
            float2 p2 = psl2[n];
            float gy = ((qgy - p2.x) * 0.5f + 1.f) * 15.f;
            float fy = floorf(gy);
            float wy = gy - fy;
            int iy = (int)fy;
            float gxb = (qgx0 - p2.y) * 7.5f + 15.f;   // + r*0.46875 per row
            const float2* row0 = &tabp2[(iy + 2) * 36 + 2];
#pragma unroll
            for (int r = 0; r < 4; ++r) {
                float gx = gxb + r * 0.46875f;
                float fx = floorf(gx);
                float wx = gx - fx;
                int ix = (int)fx;
                float2 t0 = row0[ix];
                float2 t1 = row0[ix + 36];
                float bias = (1.f - wy) * ((1.f - wx) * t0.x + wx * t0.y)
                           + wy * ((1.f - wx) * t1.x + wx * t1.y);
                s[ni][r] = s[ni][r] * 0.125f + bias;
            }
        }

        // online softmax: max via shuffles, SUM via MFMA-ones (below)
#pragma unroll
        for (int r = 0; r < 4; ++r) {
            float v = fmaxf(fmaxf(s[0][r], s[1][r]), fmaxf(s[2][r], s[3][r]));
            v = fmaxf(v, __shfl_xor(v, 1));
            v = fmaxf(v, __shfl_xor(v, 2));
            v = fmaxf(v, __shfl_xor(v, 4));
            v = fmaxf(v, __shfl_xor(v, 8));
            float mnew = fmaxf(mrun[r], v);
            float sc = __expf(mrun[r] - mnew);
            mrun[r] = mnew;
            lrun[r] *= sc;
#pragma unroll
            for (int ni = 0; ni < 4; ++ni)
                s[ni][r] = __expf(s[ni][r] - mnew);
#pragma unroll
            for (int ci = 0; ci < 4; ++ci) O[ci][r] *= sc;
        }
        // P -> LDS (bf16, per-wave tile; same-wave round trip, no barrier)
#pragma unroll
        for (int ni = 0; ni < 4; ++ni)
#pragma unroll
            for (int r = 0; r < 4; ++r)
                Plds[w][lg4 * 4 + r][ni * 16 + li] = f2us(s[ni][r]);

        bf8_t pf[2];
#pragma unroll
        for (int ks = 0; ks < 2; ++ks)
            pf[ks] = *(const bf8_t*)&Plds[w][li][ks * 32 + lg4 * 8];

        // row-sum of P via MFMA with ones-B: ps[r] = sum_n P[row][n]
        f4_t ps = (f4_t){0.f, 0.f, 0.f, 0.f};
        ps = __builtin_amdgcn_mfma_f32_16x16x32_bf16(pf[0], ones, ps, 0, 0, 0);
        ps = __builtin_amdgcn_mfma_f32_16x16x32_bf16(pf[1], ones, ps, 0, 0, 0);
#pragma unroll
        for (int r = 0; r < 4; ++r) lrun[r] += ps[r];

        // V fragments from LDS (swizzled), read after softmax
        bf8_t vf[4][2];
#pragma unroll
        for (int ci = 0; ci < 4; ++ci)
#pragma unroll
            for (int ks = 0; ks < 2; ++ks) {
                int addr = (ci * 16 + li) * 128 + ks * 64 + lg4 * 16;
                vf[ci][ks] = *(const bf8_t*)((const char*)VsS + (addr ^ ((li & 7) << 4)));
            }
#pragma unroll
        for (int ci = 0; ci < 4; ++ci) {
            O[ci] = __builtin_amdgcn_mfma_f32_16x16x32_bf16(pf[0], vf[ci][0], O[ci], 0, 0, 0);
            O[ci] = __builtin_amdgcn_mfma_f32_16x16x32_bf16(pf[1], vf[ci][1], O[ci], 0, 0, 0);
        }

        // rotate: publish next chunk's K/V
        if (chunk < 3) {
            __syncthreads();   // all waves done reading current K/V LDS
#pragma unroll
            for (int it = 0; it < 2; ++it) {
                int Li = tid + it * 256;
                int row = Li >> 3;
                int so = (Li * 16) ^ ((row & 7) << 4);
                *(us8_t*)((char*)KsS + so) = nk[it];
                *(us8_t*)((char*)VsS + so) = nv[it];
            }
            __syncthreads();   // staged data visible
        }
    }
    // epilogue
    float inv[4];
#pragma unroll
    for (int r = 0; r < 4; ++r) inv[r] = 1.f / lrun[r];
#pragma unroll
    for (int ci = 0; ci < 4; ++ci)
#pragma unroll
        for (int r = 0; r < 4; ++r) {
            int m = m0 + lg4 * 4 + r;
            ao[(size_t)(b * HWL + m) * CC + c0 + ci * 16 + li] = f2us(O[ci][r] * inv[r]);
        }
}

// -------------------- K5: final 1x1 projection (r18 tile + reg pipeline) -----
// out[b][o][m] = sum_c ao[b][m][c] * wbf[o][c]
// r18 tile (128x128, grid 768, wave 64x64 -> 2.0 MFMA/load; r19's 32x64 tile
// at 1.33 MFMA/load REGRESSED). Explicit 2-deep register pipeline on the
// K-loop (k_attn-proven pattern): issue step k+1's 8 frags before step k's
// 32 MFMAs. No launch_bounds -> allocator free (~111 regs needed).
// XCD swizzle: all 6 ot-blocks of (mt,b) on one XCD.
__global__ void k_proj(
    const u16* __restrict__ ao, const u16* __restrict__ wbf,
    float* __restrict__ out)
{
    int L = blockIdx.x;
    int xcd = L & 7;
    int t = L >> 3;            // 0..95
    int ot = t % 6;
    int gh = t / 6;            // 0..15
    int g = xcd + 8 * gh;      // 0..127 = mt + 8*b
    int mt = g & 7;
    int b = g >> 3;
    int tid = threadIdx.x;
    int w = tid >> 6, l = tid & 63;
    int li = l & 15, lg4 = l >> 4;
    int o0 = ot * 128 + (w >> 1) * 64;
    int m0 = mt * 128 + (w & 1) * 64;

    const u16* ap = ao + (size_t)b * HWL * CC;
    const u16* wp = wbf;

    f4_t acc[4][4];
#pragma unroll
    for (int i = 0; i < 4; ++i)
#pragma unroll
        for (int j = 0; j < 4; ++j) acc[i][j] = (f4_t){0.f, 0.f, 0.f, 0.f};

    // prologue: K-step 0 fragments
    bf8_t af[4][2], bfr[4][2];
#pragma unroll
    for (int i = 0; i < 4; ++i)
#pragma unroll
        for (int ks = 0; ks < 2; ++ks) {
            af[i][ks]  = *(const bf8_t*)(wp + (size_t)(o0 + i * 16 + li) * CC + ks * 32 + lg4 * 8);
            bfr[i][ks] = *(const bf8_t*)(ap + (size_t)(m0 + i * 16 + li) * CC + ks * 32 + lg4 * 8);
        }

    for (int kc = 0; kc < CC; kc += 64) {
        // issue next K-step's loads BEFORE this step's MFMAs (T14)
        bf8_t afn[4][2], bfn[4][2];
        if (kc + 64 < CC) {
            int kn = kc + 64;
#pragma unroll
            for (int i = 0; i < 4; ++i)
#pragma unroll
                for (int ks = 0; ks < 2; ++ks) {
                    afn[i][ks] = *(const bf8_t*)(wp + (size_t)(o0 + i * 16 + li) * CC + kn + ks * 32 + lg4 * 8);
                    bfn[i][ks] = *(const bf8_t*)(ap + (size_t)(m0 + i * 16 + li) * CC + kn + ks * 32 + lg4 * 8);
                }
        }
#pragma unroll
        for (int i = 0; i < 4; ++i)
#pragma unroll
            for (int j = 0; j < 4; ++j) {
                acc[i][j] = __builtin_amdgcn_mfma_f32_16x16x32_bf16(af[i][0], bfr[j][0], acc[i][j], 0, 0, 0);
                acc[i][j] = __builtin_amdgcn_mfma_f32_16x16x32_bf16(af[i][1], bfr[j][1], acc[i][j], 0, 0, 0);
            }
        if (kc + 64 < CC) {
#pragma unroll
            for (int i = 0; i < 4; ++i)
#pragma unroll
                for (int ks = 0; ks < 2; ++ks) {
                    af[i][ks]  = afn[i][ks];
                    bfr[i][ks] = bfn[i][ks];
                }
        }
    }
#pragma unroll
    for (int i = 0; i < 4; ++i)
#pragma unroll
        for (int r = 0; r < 4; ++r) {
            int o = o0 + i * 16 + lg4 * 4 + r;
            float* op = out + ((size_t)b * CC + o) * HWL + m0;
#pragma unroll
            for (int j = 0; j < 4; ++j)
                op[j * 16 + li] = acc[i][j][r];
        }
}

extern "C" void kernel_launch(void* const* d_in, const int* in_sizes, int n_in,
                              void* d_out, int out_size, void* d_ws, size_t ws_size,
                              hipStream_t stream) {
    const float* x     = (const float*)d_in[0];
    const float* wv    = (const float*)d_in[1];
    const float* bv    = (const float*)d_in[2];
    const float* wq    = (const float*)d_in[3];
    const float* bq    = (const float*)d_in[4];
    const float* wk    = (const float*)d_in[5];
    const float* bk    = (const float*)d_in[6];
    const float* wo1   = (const float*)d_in[7];
    const float* bo1   = (const float*)d_in[8];
    const float* lng   = (const float*)d_in[9];
    const float* lnb   = (const float*)d_in[10];
    const float* woff2 = (const float*)d_in[11];
    const float* rpe   = (const float*)d_in[12];
    const float* wout  = (const float*)d_in[13];
    float* out = (float*)d_out;

    char* ws = (char*)d_ws;
    size_t off = 0;
    auto alloc = [&](size_t nbytes) -> void* {
        void* p = ws + off;
        off += (nbytes + 255) & ~(size_t)255;
        return p;
    };
    u16*   value = (u16*)  alloc((size_t)BB * CC * HWL * 2);   // 25.2 MB
    u16*   query = (u16*)  alloc((size_t)BB * CC * HWL * 2);   // 25.2 MB
    u16*   key   = (u16*)  alloc((size_t)BB * CC * NS * 2);    //  6.3 MB
    float* tbuf  = (float*)alloc((size_t)BB * NS * CC * 4);    // 12.6 MB [b][c][n]
    float* pos   = (float*)alloc((size_t)BB * NS * 2 * 4);
    u16*   ao    = (u16*)  alloc((size_t)BB * HWL * CC * 2);   // 25.2 MB
    u16*   wbf   = (u16*)  alloc((size_t)CC * CC * 2);         //  1.2 MB

    // kt/vst alias tbuf (dead after k_offset): 6.3 + 6.3 = 12.6 MB exact fit
    u16* kt  = (u16*)tbuf;
    u16* vst = (u16*)((char*)tbuf + (size_t)BB * NS * CC * 2);

    k_dwconv<<<BB * CC, 256, 0, stream>>>(x, wv, bv, wq, bq, wk, bk, wo1, bo1,
                                          value, query, key, tbuf);
    k_offset<<<BB * NS, 256, 0, stream>>>(tbuf, lng, lnb, woff2, pos);
    k_sample<<<dim3(CC / 4, BB), 256, 0, stream>>>(value, pos, vst);
    k_transpose<<<dim3(NS / 64, CC / 64, BB), 256, 0, stream>>>(key, kt, CC, NS);
    k_cvtw<<<CC * CC / 1024, 256, 0, stream>>>(wout, wbf);
    k_attn<<<dim3(16 * 192), 256, 0, stream>>>(query, kt, vst, rpe, pos, ao);
    k_proj<<<dim3(768), 256, 0, stream>>>(ao, wbf, out);
}

// Round 21
// 194.288 us; speedup vs baseline: 1.5299x; 1.5299x over previous
//
#include <hip/hip_runtime.h>
#include <hip/hip_bf16.h>
#include <math.h>

typedef unsigned short u16;
typedef __attribute__((ext_vector_type(8))) short bf8_t;
typedef __attribute__((ext_vector_type(8))) unsigned short us8_t;
typedef __attribute__((ext_vector_type(4))) float f4_t;

#define BB 16
#define CC 768
#define HH 32
#define WW 32
#define HWL 1024
#define NHH 12
#define HDD 64
#define HK 16
#define NS 256
#define RT 31

__device__ inline float us2f(u16 u) {
    return __uint_as_float(((unsigned int)u) << 16);
}
__device__ inline u16 f2us(float f) {
    unsigned int u = __float_as_uint(f);
    unsigned int r = (u + 0x7fffu + ((u >> 16) & 1u)) >> 16;
    return (u16)r;
}

// -------------------- K1: all four depthwise convs (4 px/thread) -------------
__global__ __launch_bounds__(256) void k_dwconv(
    const float* __restrict__ x,
    const float* __restrict__ wv, const float* __restrict__ bv,
    const float* __restrict__ wq, const float* __restrict__ bq,
    const float* __restrict__ wk, const float* __restrict__ bk,
    const float* __restrict__ wo, const float* __restrict__ bo,
    u16* __restrict__ value, u16* __restrict__ query,
    u16* __restrict__ key, float* __restrict__ tbuf)
{
    __shared__ float xs[34 * 34];
    int blk = blockIdx.x;
    int b = blk / CC, c = blk % CC;
    int tid = threadIdx.x;
    const float* xp = x + (size_t)(b * CC + c) * HWL;

    for (int i = tid; i < 34 * 34; i += 256) {
        int r = i / 34, cc2 = i % 34;
        int gr = r - 1, gc = cc2 - 1;
        float v = 0.f;
        if (gr >= 0 && gr < 32 && gc >= 0 && gc < 32) v = xp[gr * 32 + gc];
        xs[i] = v;
    }
    float wv_[9], wq_[9], wk_[9], wo_[9];
#pragma unroll
    for (int k = 0; k < 9; ++k) {
        wv_[k] = wv[c * 9 + k];
        wq_[k] = wq[c * 9 + k];
        wk_[k] = wk[c * 9 + k];
        wo_[k] = wo[c * 9 + k];
    }
    float bv_ = bv[c], bq_ = bq[c], bk_ = bk[c], bo_ = bo[c];
    __syncthreads();

    // stride-1: 4 consecutive px per thread; 3x6 window loaded once (18 ds_reads)
    {
        int oy = tid >> 3;            // 0..31
        int ox4 = (tid & 7) * 4;      // 0,4,...,28
        float xw[3][6];
#pragma unroll
        for (int dy = 0; dy < 3; ++dy)
#pragma unroll
            for (int dx = 0; dx < 6; ++dx)
                xw[dy][dx] = xs[(oy + dy) * 34 + ox4 + dx];
        union { u16 u[4]; ushort4 v; } pv, pq;
#pragma unroll
        for (int j = 0; j < 4; ++j) {
            float av = 0.f, aq = 0.f;
#pragma unroll
            for (int dy = 0; dy < 3; ++dy)
#pragma unroll
                for (int dx = 0; dx < 3; ++dx) {
                    float xv = xw[dy][j + dx];
                    av += xv * wv_[dy * 3 + dx];
                    aq += xv * wq_[dy * 3 + dx];
                }
            pv.u[j] = f2us(av + bv_);
            pq.u[j] = f2us(aq + bq_);
        }
        size_t o = (size_t)(b * CC + c) * HWL + oy * 32 + ox4;
        *(ushort4*)&value[o] = pv.v;
        *(ushort4*)&query[o] = pq.v;
    }
    // stride-2: key (bf16 [b][c][n]), offset-pre t (f32 [b][c][n], coalesced)
    {
        int oy = tid >> 4, ox = tid & 15;
        float ak = 0.f, ao2 = 0.f;
#pragma unroll
        for (int dy = 0; dy < 3; ++dy)
#pragma unroll
            for (int dx = 0; dx < 3; ++dx) {
                float xv = xs[(2 * oy + dy) * 34 + 2 * ox + dx];
                ak += xv * wk_[dy * 3 + dx];
                ao2 += xv * wo_[dy * 3 + dx];
            }
        key[(size_t)(b * CC + c) * NS + tid] = f2us(ak + bk_);
        tbuf[(size_t)(b * CC + c) * NS + tid] = ao2 + bo_;
    }
}

// -------------------- K2: LN + GELU + 1x1 -> offsets -> pos --------------------
__global__ __launch_bounds__(256) void k_offset(
    const float* __restrict__ tbuf,
    const float* __restrict__ lng, const float* __restrict__ lnb,
    const float* __restrict__ woff2, float* __restrict__ pos)
{
    __shared__ float sm[16];
    int blk = blockIdx.x;
    int b = blk >> 8;
    int n = blk & 255;
    int tid = threadIdx.x;
    const float* tp = tbuf + (size_t)b * CC * NS + n;
    float tv0 = tp[(size_t)tid * NS];
    float tv1 = tp[(size_t)(tid + 256) * NS];
    float tv2 = tp[(size_t)(tid + 512) * NS];
    float s = tv0 + tv1 + tv2;
    float sq = tv0 * tv0 + tv1 * tv1 + tv2 * tv2;
    for (int o = 32; o; o >>= 1) { s += __shfl_down(s, o); sq += __shfl_down(sq, o); }
    int w = tid >> 6;
    if ((tid & 63) == 0) { sm[w] = s; sm[4 + w] = sq; }
    __syncthreads();
    float st = sm[0] + sm[1] + sm[2] + sm[3];
    float sqt = sm[4] + sm[5] + sm[6] + sm[7];
    float mean = st * (1.f / 768.f);
    float var = sqt * (1.f / 768.f) - mean * mean;
    float rstd = rsqrtf(fmaxf(var, 0.f) + 1e-5f);

    float oy = 0.f, ox = 0.f;
#pragma unroll
    for (int j = 0; j < 3; ++j) {
        int c = tid + j * 256;
        float tvj = (j == 0) ? tv0 : ((j == 1) ? tv1 : tv2);
        float xn = (tvj - mean) * rstd;
        float y = xn * lng[c] + lnb[c];
        float ge = 0.5f * y * (1.f + erff(y * 0.70710678118654752f));
        oy += ge * woff2[c];
        ox += ge * woff2[CC + c];
    }
    for (int o = 32; o; o >>= 1) { oy += __shfl_down(oy, o); ox += __shfl_down(ox, o); }
    __syncthreads();
    if ((tid & 63) == 0) { sm[w] = oy; sm[8 + w] = ox; }
    __syncthreads();
    if (tid == 0) {
        float oyt = sm[0] + sm[1] + sm[2] + sm[3];
        float oxt = sm[8] + sm[9] + sm[10] + sm[11];
        float offy = tanhf(oyt) * 0.125f;
        float offx = tanhf(oxt) * 0.125f;
        int ky = n >> 4, kx = n & 15;
        pos[blk * 2 + 0] = (ky + 0.5f) * 0.125f - 1.f + offy;
        pos[blk * 2 + 1] = (kx + 0.5f) * 0.125f - 1.f + offx;
    }
}

// -------------------- K3: sample value at pos -> vst [b][c][n] directly ------
__global__ __launch_bounds__(256) void k_sample(
    const u16* __restrict__ value, const float* __restrict__ pos,
    u16* __restrict__ vst)
{
    __shared__ float psl[NS * 2];
    int cg = blockIdx.x;
    int b  = blockIdx.y;
    int tid = threadIdx.x;
    for (int i = tid; i < NS * 2; i += 256) psl[i] = pos[b * NS * 2 + i];
    __syncthreads();
    int c = cg * 4 + (tid >> 6);
    int nl = tid & 63;
    const u16* vp = value + (size_t)(b * CC + c) * HWL;
    u16* op = vst + (size_t)(b * CC + c) * NS;
#pragma unroll
    for (int j = 0; j < 4; ++j) {
        int n = j * 64 + nl;
        float py = psl[2 * n], px = psl[2 * n + 1];
        float gx = (px + 1.f) * 15.5f;
        float gy = (py + 1.f) * 15.5f;
        float fx = floorf(gx), fy = floorf(gy);
        float wx = gx - fx, wy = gy - fy;
        int ix0 = (int)fx, iy0 = (int)fy;
        int ix1 = ix0 + 1, iy1 = iy0 + 1;
        float m00 = ((unsigned)ix0 < 32u && (unsigned)iy0 < 32u) ? 1.f : 0.f;
        float m01 = ((unsigned)ix1 < 32u && (unsigned)iy0 < 32u) ? 1.f : 0.f;
        float m10 = ((unsigned)ix0 < 32u && (unsigned)iy1 < 32u) ? 1.f : 0.f;
        float m11 = ((unsigned)ix1 < 32u && (unsigned)iy1 < 32u) ? 1.f : 0.f;
        int cx0 = min(max(ix0, 0), 31), cx1 = min(max(ix1, 0), 31);
        int cy0 = min(max(iy0, 0), 31), cy1 = min(max(iy1, 0), 31);
        float w00 = (1.f - wy) * (1.f - wx) * m00;
        float w01 = (1.f - wy) * wx * m01;
        float w10 = wy * (1.f - wx) * m10;
        float w11 = wy * wx * m11;
        float r = w00 * us2f(vp[cy0 * 32 + cx0]) + w01 * us2f(vp[cy0 * 32 + cx1])
                + w10 * us2f(vp[cy1 * 32 + cx0]) + w11 * us2f(vp[cy1 * 32 + cx1]);
        op[n] = f2us(r);
    }
}

// -------------------- K3b: batched 64x64 bf16 transpose (key -> kt) ----------
__global__ __launch_bounds__(256) void k_transpose(
    const u16* __restrict__ in, u16* __restrict__ out, int R, int S)
{
    __shared__ u16 tile[64][68];
    int bx = blockIdx.x;
    int by = blockIdx.y;
    int bz = blockIdx.z;
    int t = threadIdx.x;
    int ci = (t & 15) * 4;
    int ri = t >> 4;
    const u16* ip = in + (size_t)bz * R * S;
    u16* op = out + (size_t)bz * R * S;
#pragma unroll
    for (int i = 0; i < 4; ++i) {
        int r = ri + i * 16;
        ushort4 v = *(const ushort4*)(ip + (size_t)(by * 64 + r) * S + bx * 64 + ci);
        *(ushort4*)&tile[r][ci] = v;
    }
    __syncthreads();
#pragma unroll
    for (int i = 0; i < 4; ++i) {
        int s = ri + i * 16;
        ushort4 v;
        v.x = tile[ci + 0][s];
        v.y = tile[ci + 1][s];
        v.z = tile[ci + 2][s];
        v.w = tile[ci + 3][s];
        *(ushort4*)(op + (size_t)(bx * 64 + s) * R + by * 64 + ci) = v;
    }
}

// -------------------- K3c: wout f32 -> bf16 ----------------------------------
__global__ __launch_bounds__(256) void k_cvtw(
    const float* __restrict__ w, u16* __restrict__ wbf)
{
    int i = (blockIdx.x * 256 + threadIdx.x) * 4;
    float4 v = *(const float4*)(w + i);
    union { u16 u[4]; ushort4 v; } pk;
    pk.u[0] = f2us(v.x); pk.u[1] = f2us(v.y);
    pk.u[2] = f2us(v.z); pk.u[3] = f2us(v.w);
    *(ushort4*)(wbf + i) = pk.v;
}

// -------------------- K4: MFMA fused attention (r18 — LDS-staged K/V) --------
__global__ __launch_bounds__(256, 4) void k_attn(
    const u16* __restrict__ query, const u16* __restrict__ kt,
    const u16* __restrict__ vst, const float* __restrict__ rpe,
    const float* __restrict__ pos, u16* __restrict__ ao)
{
    __shared__ float2 tabp2[35 * 36];  // .x=tab[r][c], .y=tab[r][c+1] (padded +2)
    __shared__ float2 psl2[NS];
    __shared__ u16 Plds[4][16][72];
    __shared__ u16 KsS[4096];          // 64 rows x 64 bf16, XOR-swizzled
    __shared__ u16 VsS[4096];

    int L = blockIdx.x;
    int xcd = L & 7;
    int t2 = L >> 3;
    int mt = t2 & 15;          // m tile of 64
    int bh = xcd + 8 * (t2 >> 4);
    int b = bh / NHH, h = bh % NHH;
    int tid = threadIdx.x;
    int w = tid >> 6;
    int l = tid & 63;
    int li = l & 15, lg4 = l >> 4;

    for (int i = tid; i < 35 * 36; i += 256) {
        int r = i / 36, c = i % 36;
        int rr = r - 2;
        int c0i = c - 2, c1i = c - 1;
        float v0 = ((unsigned)rr < 31u && (unsigned)c0i < 31u)
                       ? rpe[h * RT * RT + rr * RT + c0i] : 0.f;
        float v1 = ((unsigned)rr < 31u && (unsigned)c1i < 31u)
                       ? rpe[h * RT * RT + rr * RT + c1i] : 0.f;
        tabp2[i] = make_float2(v0, v1);
    }
    for (int i = tid; i < NS; i += 256) {
        psl2[i] = make_float2(pos[b * NS * 2 + 2 * i], pos[b * NS * 2 + 2 * i + 1]);
    }

    int c0 = h * 64;

    // prologue: stage chunk 0 K/V (reg-staged, swizzled write)
#pragma unroll
    for (int it = 0; it < 2; ++it) {
        int Li = tid + it * 256;          // 0..511
        int row = Li >> 3;                // 0..63
        int colb = (Li & 7) * 16;         // byte col within 128B row
        us8_t kv = *(const us8_t*)(kt  + (size_t)(b * NS + row) * CC + c0 + colb / 2);
        us8_t vv = *(const us8_t*)(vst + (size_t)(b * CC + c0 + row) * NS + colb / 2);
        int so = (Li * 16) ^ ((row & 7) << 4);
        *(us8_t*)((char*)KsS + so) = kv;
        *(us8_t*)((char*)VsS + so) = vv;
    }
    __syncthreads();

    int m0 = mt * 64 + w * 16;

    // Q fragments directly from query [b][c][m]: row=li(m), k=c
    bf8_t qf[2];
#pragma unroll
    for (int ks = 0; ks < 2; ++ks) {
        union { short s[8]; bf8_t v; } u;
#pragma unroll
        for (int j = 0; j < 8; ++j)
            u.s[j] = (short)query[(size_t)(b * CC + c0 + ks * 32 + lg4 * 8 + j) * HWL + m0 + li];
        qf[ks] = u.v;
    }
    // all-ones B fragment (bf16 1.0) for MFMA row-sum
    bf8_t ones;
    {
        union { short s[8]; bf8_t v; } u;
#pragma unroll
        for (int j = 0; j < 8; ++j) u.s[j] = (short)0x3F80;
        ones = u.v;
    }

    f4_t O[4];
#pragma unroll
    for (int ci = 0; ci < 4; ++ci) O[ci] = (f4_t){0.f, 0.f, 0.f, 0.f};
    float mrun[4], lrun[4];
#pragma unroll
    for (int r = 0; r < 4; ++r) { mrun[r] = -1e30f; lrun[r] = 0.f; }

    int mrow = m0 + lg4 * 4;
    float qgy  = ((mrow >> 5) + 0.5f) * 0.0625f - 1.f;
    float qgx0 = ((mrow & 31) + 0.5f) * 0.0625f - 1.f;

    for (int chunk = 0; chunk < 4; ++chunk) {
        int n0 = chunk * 64;

        // K fragments from LDS (swizzled read, 2-way free)
        bf8_t kf[4][2];
#pragma unroll
        for (int ni = 0; ni < 4; ++ni)
#pragma unroll
            for (int ks = 0; ks < 2; ++ks) {
                int addr = (ni * 16 + li) * 128 + ks * 64 + lg4 * 16;
                kf[ni][ks] = *(const bf8_t*)((const char*)KsS + (addr ^ ((li & 7) << 4)));
            }

        // T14: issue next chunk's global loads early (latency hides under compute)
        us8_t nk[2], nv[2];
        if (chunk < 3) {
            int n1 = n0 + 64;
#pragma unroll
            for (int it = 0; it < 2; ++it) {
                int Li = tid + it * 256;
                int row = Li >> 3;
                int colb = (Li & 7) * 16;
                nk[it] = *(const us8_t*)(kt  + (size_t)(b * NS + n1 + row) * CC + c0 + colb / 2);
                nv[it] = *(const us8_t*)(vst + (size_t)(b * CC + c0 + row) * NS + n1 + colb / 2);
            }
        }

        f4_t s[4];
#pragma unroll
        for (int ni = 0; ni < 4; ++ni) {
            f4_t acc = (f4_t){0.f, 0.f, 0.f, 0.f};
            acc = __builtin_amdgcn_mfma_f32_16x16x32_bf16(qf[0], kf[ni][0], acc, 0, 0, 0);
            acc = __builtin_amdgcn_mfma_f32_16x16x32_bf16(qf[1], kf[ni][1], acc, 0, 0, 0);
            s[ni] = acc;
        }

        // scale + RPE bias (C-layout: col n = li, row m = lg4*4+r)
#pragma unroll
        for (int ni = 0; ni < 4; ++ni) {
            int n = n0 + ni * 16 + li;
            float2 p2 = psl2[n];
            float gy = ((qgy - p2.x) * 0.5f + 1.f) * 15.f;
            float fy = floorf(gy);
            float wy = gy - fy;
            int iy = (int)fy;
            float gxb = (qgx0 - p2.y) * 7.5f + 15.f;   // + r*0.46875 per row
            const float2* row0 = &tabp2[(iy + 2) * 36 + 2];
#pragma unroll
            for (int r = 0; r < 4; ++r) {
                float gx = gxb + r * 0.46875f;
                float fx = floorf(gx);
                float wx = gx - fx;
                int ix = (int)fx;
                float2 t0 = row0[ix];
                float2 t1 = row0[ix + 36];
                float bias = (1.f - wy) * ((1.f - wx) * t0.x + wx * t0.y)
                           + wy * ((1.f - wx) * t1.x + wx * t1.y);
                s[ni][r] = s[ni][r] * 0.125f + bias;
            }
        }

        // online softmax: max via shuffles, SUM via MFMA-ones (below)
#pragma unroll
        for (int r = 0; r < 4; ++r) {
            float v = fmaxf(fmaxf(s[0][r], s[1][r]), fmaxf(s[2][r], s[3][r]));
            v = fmaxf(v, __shfl_xor(v, 1));
            v = fmaxf(v, __shfl_xor(v, 2));
            v = fmaxf(v, __shfl_xor(v, 4));
            v = fmaxf(v, __shfl_xor(v, 8));
            float mnew = fmaxf(mrun[r], v);
            float sc = __expf(mrun[r] - mnew);
            mrun[r] = mnew;
            lrun[r] *= sc;
#pragma unroll
            for (int ni = 0; ni < 4; ++ni)
                s[ni][r] = __expf(s[ni][r] - mnew);
#pragma unroll
            for (int ci = 0; ci < 4; ++ci) O[ci][r] *= sc;
        }
        // P -> LDS (bf16, per-wave tile; same-wave round trip, no barrier)
#pragma unroll
        for (int ni = 0; ni < 4; ++ni)
#pragma unroll
            for (int r = 0; r < 4; ++r)
                Plds[w][lg4 * 4 + r][ni * 16 + li] = f2us(s[ni][r]);

        bf8_t pf[2];
#pragma unroll
        for (int ks = 0; ks < 2; ++ks)
            pf[ks] = *(const bf8_t*)&Plds[w][li][ks * 32 + lg4 * 8];

        // row-sum of P via MFMA with ones-B: ps[r] = sum_n P[row][n]
        f4_t ps = (f4_t){0.f, 0.f, 0.f, 0.f};
        ps = __builtin_amdgcn_mfma_f32_16x16x32_bf16(pf[0], ones, ps, 0, 0, 0);
        ps = __builtin_amdgcn_mfma_f32_16x16x32_bf16(pf[1], ones, ps, 0, 0, 0);
#pragma unroll
        for (int r = 0; r < 4; ++r) lrun[r] += ps[r];

        // V fragments from LDS (swizzled), read after softmax
        bf8_t vf[4][2];
#pragma unroll
        for (int ci = 0; ci < 4; ++ci)
#pragma unroll
            for (int ks = 0; ks < 2; ++ks) {
                int addr = (ci * 16 + li) * 128 + ks * 64 + lg4 * 16;
                vf[ci][ks] = *(const bf8_t*)((const char*)VsS + (addr ^ ((li & 7) << 4)));
            }
#pragma unroll
        for (int ci = 0; ci < 4; ++ci) {
            O[ci] = __builtin_amdgcn_mfma_f32_16x16x32_bf16(pf[0], vf[ci][0], O[ci], 0, 0, 0);
            O[ci] = __builtin_amdgcn_mfma_f32_16x16x32_bf16(pf[1], vf[ci][1], O[ci], 0, 0, 0);
        }

        // rotate: publish next chunk's K/V
        if (chunk < 3) {
            __syncthreads();   // all waves done reading current K/V LDS
#pragma unroll
            for (int it = 0; it < 2; ++it) {
                int Li = tid + it * 256;
                int row = Li >> 3;
                int so = (Li * 16) ^ ((row & 7) << 4);
                *(us8_t*)((char*)KsS + so) = nk[it];
                *(us8_t*)((char*)VsS + so) = nv[it];
            }
            __syncthreads();   // staged data visible
        }
    }
    // epilogue
    float inv[4];
#pragma unroll
    for (int r = 0; r < 4; ++r) inv[r] = 1.f / lrun[r];
#pragma unroll
    for (int ci = 0; ci < 4; ++ci)
#pragma unroll
        for (int r = 0; r < 4; ++r) {
            int m = m0 + lg4 * 4 + r;
            ao[(size_t)(b * HWL + m) * CC + c0 + ci * 16 + li] = f2us(O[ci][r] * inv[r]);
        }
}

// -------------------- K5: final 1x1 projection (r18-exact MFMA GEMM) ---------
// out[b][o][m] = sum_c ao[b][m][c] * wbf[o][c]
// 128x128 tile, grid 768, wave 64x64 (2.0 MFMA/load). MEASURED BEST: 98 us,
// VGPR 100, WRITE 49 MB. Ruled out: 32x64 tile (r19, lower intensity, 104 us),
// 2-deep reg pipeline (r20, spill to 553 MB scratch, 176 us). Reg pipelines
// over 64-wide acc tiles don't fit gfx950's budget — staging must be LDS.
// XCD swizzle: all 6 ot-blocks of (mt,b) on one XCD -> ao panel cached once.
__global__ __launch_bounds__(256) void k_proj(
    const u16* __restrict__ ao, const u16* __restrict__ wbf,
    float* __restrict__ out)
{
    int L = blockIdx.x;
    int xcd = L & 7;
    int t = L >> 3;            // 0..95
    int ot = t % 6;
    int gh = t / 6;            // 0..15
    int g = xcd + 8 * gh;      // 0..127 = mt + 8*b
    int mt = g & 7;
    int b = g >> 3;
    int tid = threadIdx.x;
    int w = tid >> 6, l = tid & 63;
    int li = l & 15, lg4 = l >> 4;
    int o0 = ot * 128 + (w >> 1) * 64;
    int m0 = mt * 128 + (w & 1) * 64;

    const u16* ap = ao + (size_t)b * HWL * CC;

    f4_t acc[4][4];
#pragma unroll
    for (int i = 0; i < 4; ++i)
#pragma unroll
        for (int j = 0; j < 4; ++j) acc[i][j] = (f4_t){0.f, 0.f, 0.f, 0.f};

#pragma unroll 2
    for (int kc = 0; kc < CC; kc += 64) {
        bf8_t af[4][2], bfr[4][2];
#pragma unroll
        for (int i = 0; i < 4; ++i)
#pragma unroll
            for (int ks = 0; ks < 2; ++ks) {
                af[i][ks]  = *(const bf8_t*)(wbf + (size_t)(o0 + i * 16 + li) * CC + kc + ks * 32 + lg4 * 8);
                bfr[i][ks] = *(const bf8_t*)(ap  + (size_t)(m0 + i * 16 + li) * CC + kc + ks * 32 + lg4 * 8);
            }
#pragma unroll
        for (int i = 0; i < 4; ++i)
#pragma unroll
            for (int j = 0; j < 4; ++j) {
                acc[i][j] = __builtin_amdgcn_mfma_f32_16x16x32_bf16(af[i][0], bfr[j][0], acc[i][j], 0, 0, 0);
                acc[i][j] = __builtin_amdgcn_mfma_f32_16x16x32_bf16(af[i][1], bfr[j][1], acc[i][j], 0, 0, 0);
            }
    }
#pragma unroll
    for (int i = 0; i < 4; ++i)
#pragma unroll
        for (int r = 0; r < 4; ++r) {
            int o = o0 + i * 16 + lg4 * 4 + r;
            float* op = out + ((size_t)b * CC + o) * HWL + m0;
#pragma unroll
            for (int j = 0; j < 4; ++j)
                op[j * 16 + li] = acc[i][j][r];
        }
}

extern "C" void kernel_launch(void* const* d_in, const int* in_sizes, int n_in,
                              void* d_out, int out_size, void* d_ws, size_t ws_size,
                              hipStream_t stream) {
    const float* x     = (const float*)d_in[0];
    const float* wv    = (const float*)d_in[1];
    const float* bv    = (const float*)d_in[2];
    const float* wq    = (const float*)d_in[3];
    const float* bq    = (const float*)d_in[4];
    const float* wk    = (const float*)d_in[5];
    const float* bk    = (const float*)d_in[6];
    const float* wo1   = (const float*)d_in[7];
    const float* bo1   = (const float*)d_in[8];
    const float* lng   = (const float*)d_in[9];
    const float* lnb   = (const float*)d_in[10];
    const float* woff2 = (const float*)d_in[11];
    const float* rpe   = (const float*)d_in[12];
    const float* wout  = (const float*)d_in[13];
    float* out = (float*)d_out;

    char* ws = (char*)d_ws;
    size_t off = 0;
    auto alloc = [&](size_t nbytes) -> void* {
        void* p = ws + off;
        off += (nbytes + 255) & ~(size_t)255;
        return p;
    };
    u16*   value = (u16*)  alloc((size_t)BB * CC * HWL * 2);   // 25.2 MB
    u16*   query = (u16*)  alloc((size_t)BB * CC * HWL * 2);   // 25.2 MB
    u16*   key   = (u16*)  alloc((size_t)BB * CC * NS * 2);    //  6.3 MB
    float* tbuf  = (float*)alloc((size_t)BB * NS * CC * 4);    // 12.6 MB [b][c][n]
    float* pos   = (float*)alloc((size_t)BB * NS * 2 * 4);
    u16*   ao    = (u16*)  alloc((size_t)BB * HWL * CC * 2);   // 25.2 MB
    u16*   wbf   = (u16*)  alloc((size_t)CC * CC * 2);         //  1.2 MB

    // kt/vst alias tbuf (dead after k_offset): 6.3 + 6.3 = 12.6 MB exact fit
    u16* kt  = (u16*)tbuf;
    u16* vst = (u16*)((char*)tbuf + (size_t)BB * NS * CC * 2);

    k_dwconv<<<BB * CC, 256, 0, stream>>>(x, wv, bv, wq, bq, wk, bk, wo1, bo1,
                                          value, query, key, tbuf);
    k_offset<<<BB * NS, 256, 0, stream>>>(tbuf, lng, lnb, woff2, pos);
    k_sample<<<dim3(CC / 4, BB), 256, 0, stream>>>(value, pos, vst);
    k_transpose<<<dim3(NS / 64, CC / 64, BB), 256, 0, stream>>>(key, kt, CC, NS);
    k_cvtw<<<CC * CC / 1024, 256, 0, stream>>>(wout, wbf);
    k_attn<<<dim3(16 * 192), 256, 0, stream>>>(query, kt, vst, rpe, pos, ao);
    k_proj<<<dim3(768), 256, 0, stream>>>(ao, wbf, out);
}

// Round 22
// 191.115 us; speedup vs baseline: 1.5553x; 1.0166x over previous
//
#include <hip/hip_runtime.h>
#include <hip/hip_bf16.h>
#include <math.h>

typedef unsigned short u16;
typedef __attribute__((ext_vector_type(8))) short bf8_t;
typedef __attribute__((ext_vector_type(8))) unsigned short us8_t;
typedef __attribute__((ext_vector_type(4))) float f4_t;

#define BB 16
#define CC 768
#define HH 32
#define WW 32
#define HWL 1024
#define NHH 12
#define HDD 64
#define HK 16
#define NS 256
#define RT 31

__device__ inline float us2f(u16 u) {
    return __uint_as_float(((unsigned int)u) << 16);
}
__device__ inline u16 f2us(float f) {
    unsigned int u = __float_as_uint(f);
    unsigned int r = (u + 0x7fffu + ((u >> 16) & 1u)) >> 16;
    return (u16)r;
}

// -------------------- K1: all four depthwise convs (4 px/thread) -------------
__global__ __launch_bounds__(256) void k_dwconv(
    const float* __restrict__ x,
    const float* __restrict__ wv, const float* __restrict__ bv,
    const float* __restrict__ wq, const float* __restrict__ bq,
    const float* __restrict__ wk, const float* __restrict__ bk,
    const float* __restrict__ wo, const float* __restrict__ bo,
    u16* __restrict__ value, u16* __restrict__ query,
    u16* __restrict__ key, float* __restrict__ tbuf)
{
    __shared__ float xs[34 * 34];
    int blk = blockIdx.x;
    int b = blk / CC, c = blk % CC;
    int tid = threadIdx.x;
    const float* xp = x + (size_t)(b * CC + c) * HWL;

    for (int i = tid; i < 34 * 34; i += 256) {
        int r = i / 34, cc2 = i % 34;
        int gr = r - 1, gc = cc2 - 1;
        float v = 0.f;
        if (gr >= 0 && gr < 32 && gc >= 0 && gc < 32) v = xp[gr * 32 + gc];
        xs[i] = v;
    }
    float wv_[9], wq_[9], wk_[9], wo_[9];
#pragma unroll
    for (int k = 0; k < 9; ++k) {
        wv_[k] = wv[c * 9 + k];
        wq_[k] = wq[c * 9 + k];
        wk_[k] = wk[c * 9 + k];
        wo_[k] = wo[c * 9 + k];
    }
    float bv_ = bv[c], bq_ = bq[c], bk_ = bk[c], bo_ = bo[c];
    __syncthreads();

    // stride-1: 4 consecutive px per thread; 3x6 window loaded once (18 ds_reads)
    {
        int oy = tid >> 3;            // 0..31
        int ox4 = (tid & 7) * 4;      // 0,4,...,28
        float xw[3][6];
#pragma unroll
        for (int dy = 0; dy < 3; ++dy)
#pragma unroll
            for (int dx = 0; dx < 6; ++dx)
                xw[dy][dx] = xs[(oy + dy) * 34 + ox4 + dx];
        union { u16 u[4]; ushort4 v; } pv, pq;
#pragma unroll
        for (int j = 0; j < 4; ++j) {
            float av = 0.f, aq = 0.f;
#pragma unroll
            for (int dy = 0; dy < 3; ++dy)
#pragma unroll
                for (int dx = 0; dx < 3; ++dx) {
                    float xv = xw[dy][j + dx];
                    av += xv * wv_[dy * 3 + dx];
                    aq += xv * wq_[dy * 3 + dx];
                }
            pv.u[j] = f2us(av + bv_);
            pq.u[j] = f2us(aq + bq_);
        }
        size_t o = (size_t)(b * CC + c) * HWL + oy * 32 + ox4;
        *(ushort4*)&value[o] = pv.v;
        *(ushort4*)&query[o] = pq.v;
    }
    // stride-2: key (bf16 [b][c][n]), offset-pre t (f32 [b][c][n], coalesced)
    {
        int oy = tid >> 4, ox = tid & 15;
        float ak = 0.f, ao2 = 0.f;
#pragma unroll
        for (int dy = 0; dy < 3; ++dy)
#pragma unroll
            for (int dx = 0; dx < 3; ++dx) {
                float xv = xs[(2 * oy + dy) * 34 + 2 * ox + dx];
                ak += xv * wk_[dy * 3 + dx];
                ao2 += xv * wo_[dy * 3 + dx];
            }
        key[(size_t)(b * CC + c) * NS + tid] = f2us(ak + bk_);
        tbuf[(size_t)(b * CC + c) * NS + tid] = ao2 + bo_;
    }
}

// -------------------- K2: LN + GELU + 1x1 -> offsets -> pos --------------------
__global__ __launch_bounds__(256) void k_offset(
    const float* __restrict__ tbuf,
    const float* __restrict__ lng, const float* __restrict__ lnb,
    const float* __restrict__ woff2, float* __restrict__ pos)
{
    __shared__ float sm[16];
    int blk = blockIdx.x;
    int b = blk >> 8;
    int n = blk & 255;
    int tid = threadIdx.x;
    const float* tp = tbuf + (size_t)b * CC * NS + n;
    float tv0 = tp[(size_t)tid * NS];
    float tv1 = tp[(size_t)(tid + 256) * NS];
    float tv2 = tp[(size_t)(tid + 512) * NS];
    float s = tv0 + tv1 + tv2;
    float sq = tv0 * tv0 + tv1 * tv1 + tv2 * tv2;
    for (int o = 32; o; o >>= 1) { s += __shfl_down(s, o); sq += __shfl_down(sq, o); }
    int w = tid >> 6;
    if ((tid & 63) == 0) { sm[w] = s; sm[4 + w] = sq; }
    __syncthreads();
    float st = sm[0] + sm[1] + sm[2] + sm[3];
    float sqt = sm[4] + sm[5] + sm[6] + sm[7];
    float mean = st * (1.f / 768.f);
    float var = sqt * (1.f / 768.f) - mean * mean;
    float rstd = rsqrtf(fmaxf(var, 0.f) + 1e-5f);

    float oy = 0.f, ox = 0.f;
#pragma unroll
    for (int j = 0; j < 3; ++j) {
        int c = tid + j * 256;
        float tvj = (j == 0) ? tv0 : ((j == 1) ? tv1 : tv2);
        float xn = (tvj - mean) * rstd;
        float y = xn * lng[c] + lnb[c];
        float ge = 0.5f * y * (1.f + erff(y * 0.70710678118654752f));
        oy += ge * woff2[c];
        ox += ge * woff2[CC + c];
    }
    for (int o = 32; o; o >>= 1) { oy += __shfl_down(oy, o); ox += __shfl_down(ox, o); }
    __syncthreads();
    if ((tid & 63) == 0) { sm[w] = oy; sm[8 + w] = ox; }
    __syncthreads();
    if (tid == 0) {
        float oyt = sm[0] + sm[1] + sm[2] + sm[3];
        float oxt = sm[8] + sm[9] + sm[10] + sm[11];
        float offy = tanhf(oyt) * 0.125f;
        float offx = tanhf(oxt) * 0.125f;
        int ky = n >> 4, kx = n & 15;
        pos[blk * 2 + 0] = (ky + 0.5f) * 0.125f - 1.f + offy;
        pos[blk * 2 + 1] = (kx + 0.5f) * 0.125f - 1.f + offx;
    }
}

// -------------------- K3: sample value at pos -> vst [b][c][n] directly ------
__global__ __launch_bounds__(256) void k_sample(
    const u16* __restrict__ value, const float* __restrict__ pos,
    u16* __restrict__ vst)
{
    __shared__ float psl[NS * 2];
    int cg = blockIdx.x;
    int b  = blockIdx.y;
    int tid = threadIdx.x;
    for (int i = tid; i < NS * 2; i += 256) psl[i] = pos[b * NS * 2 + i];
    __syncthreads();
    int c = cg * 4 + (tid >> 6);
    int nl = tid & 63;
    const u16* vp = value + (size_t)(b * CC + c) * HWL;
    u16* op = vst + (size_t)(b * CC + c) * NS;
#pragma unroll
    for (int j = 0; j < 4; ++j) {
        int n = j * 64 + nl;
        float py = psl[2 * n], px = psl[2 * n + 1];
        float gx = (px + 1.f) * 15.5f;
        float gy = (py + 1.f) * 15.5f;
        float fx = floorf(gx), fy = floorf(gy);
        float wx = gx - fx, wy = gy - fy;
        int ix0 = (int)fx, iy0 = (int)fy;
        int ix1 = ix0 + 1, iy1 = iy0 + 1;
        float m00 = ((unsigned)ix0 < 32u && (unsigned)iy0 < 32u) ? 1.f : 0.f;
        float m01 = ((unsigned)ix1 < 32u && (unsigned)iy0 < 32u) ? 1.f : 0.f;
        float m10 = ((unsigned)ix0 < 32u && (unsigned)iy1 < 32u) ? 1.f : 0.f;
        float m11 = ((unsigned)ix1 < 32u && (unsigned)iy1 < 32u) ? 1.f : 0.f;
        int cx0 = min(max(ix0, 0), 31), cx1 = min(max(ix1, 0), 31);
        int cy0 = min(max(iy0, 0), 31), cy1 = min(max(iy1, 0), 31);
        float w00 = (1.f - wy) * (1.f - wx) * m00;
        float w01 = (1.f - wy) * wx * m01;
        float w10 = wy * (1.f - wx) * m10;
        float w11 = wy * wx * m11;
        float r = w00 * us2f(vp[cy0 * 32 + cx0]) + w01 * us2f(vp[cy0 * 32 + cx1])
                + w10 * us2f(vp[cy1 * 32 + cx0]) + w11 * us2f(vp[cy1 * 32 + cx1]);
        op[n] = f2us(r);
    }
}

// -------------------- K3b: batched 64x64 bf16 transpose (key -> kt) ----------
__global__ __launch_bounds__(256) void k_transpose(
    const u16* __restrict__ in, u16* __restrict__ out, int R, int S)
{
    __shared__ u16 tile[64][68];
    int bx = blockIdx.x;
    int by = blockIdx.y;
    int bz = blockIdx.z;
    int t = threadIdx.x;
    int ci = (t & 15) * 4;
    int ri = t >> 4;
    const u16* ip = in + (size_t)bz * R * S;
    u16* op = out + (size_t)bz * R * S;
#pragma unroll
    for (int i = 0; i < 4; ++i) {
        int r = ri + i * 16;
        ushort4 v = *(const ushort4*)(ip + (size_t)(by * 64 + r) * S + bx * 64 + ci);
        *(ushort4*)&tile[r][ci] = v;
    }
    __syncthreads();
#pragma unroll
    for (int i = 0; i < 4; ++i) {
        int s = ri + i * 16;
        ushort4 v;
        v.x = tile[ci + 0][s];
        v.y = tile[ci + 1][s];
        v.z = tile[ci + 2][s];
        v.w = tile[ci + 3][s];
        *(ushort4*)(op + (size_t)(bx * 64 + s) * R + by * 64 + ci) = v;
    }
}

// -------------------- K3c: wout f32 -> bf16 ----------------------------------
__global__ __launch_bounds__(256) void k_cvtw(
    const float* __restrict__ w, u16* __restrict__ wbf)
{
    int i = (blockIdx.x * 256 + threadIdx.x) * 4;
    float4 v = *(const float4*)(w + i);
    union { u16 u[4]; ushort4 v; } pk;
    pk.u[0] = f2us(v.x); pk.u[1] = f2us(v.y);
    pk.u[2] = f2us(v.z); pk.u[3] = f2us(v.w);
    *(ushort4*)(wbf + i) = pk.v;
}

// -------------------- K4: MFMA fused attention (r18 — LDS-staged K/V) --------
__global__ __launch_bounds__(256, 4) void k_attn(
    const u16* __restrict__ query, const u16* __restrict__ kt,
    const u16* __restrict__ vst, const float* __restrict__ rpe,
    const float* __restrict__ pos, u16* __restrict__ ao)
{
    __shared__ float2 tabp2[35 * 36];  // .x=tab[r][c], .y=tab[r][c+1] (padded +2)
    __shared__ float2 psl2[NS];
    __shared__ u16 Plds[4][16][72];
    __shared__ u16 KsS[4096];          // 64 rows x 64 bf16, XOR-swizzled
    __shared__ u16 VsS[4096];

    int L = blockIdx.x;
    int xcd = L & 7;
    int t2 = L >> 3;
    int mt = t2 & 15;          // m tile of 64
    int bh = xcd + 8 * (t2 >> 4);
    int b = bh / NHH, h = bh % NHH;
    int tid = threadIdx.x;
    int w = tid >> 6;
    int l = tid & 63;
    int li = l & 15, lg4 = l >> 4;

    for (int i = tid; i < 35 * 36; i += 256) {
        int r = i / 36, c = i % 36;
        int rr = r - 2;
        int c0i = c - 2, c1i = c - 1;
        float v0 = ((unsigned)rr < 31u && (unsigned)c0i < 31u)
                       ? rpe[h * RT * RT + rr * RT + c0i] : 0.f;
        float v1 = ((unsigned)rr < 31u && (unsigned)c1i < 31u)
                       ? rpe[h * RT * RT + rr * RT + c1i] : 0.f;
        tabp2[i] = make_float2(v0, v1);
    }
    for (int i = tid; i < NS; i += 256) {
        psl2[i] = make_float2(pos[b * NS * 2 + 2 * i], pos[b * NS * 2 + 2 * i + 1]);
    }

    int c0 = h * 64;

    // prologue: stage chunk 0 K/V (reg-staged, swizzled write)
#pragma unroll
    for (int it = 0; it < 2; ++it) {
        int Li = tid + it * 256;          // 0..511
        int row = Li >> 3;                // 0..63
        int colb = (Li & 7) * 16;         // byte col within 128B row
        us8_t kv = *(const us8_t*)(kt  + (size_t)(b * NS + row) * CC + c0 + colb / 2);
        us8_t vv = *(const us8_t*)(vst + (size_t)(b * CC + c0 + row) * NS + colb / 2);
        int so = (Li * 16) ^ ((row & 7) << 4);
        *(us8_t*)((char*)KsS + so) = kv;
        *(us8_t*)((char*)VsS + so) = vv;
    }
    __syncthreads();

    int m0 = mt * 64 + w * 16;

    // Q fragments directly from query [b][c][m]: row=li(m), k=c
    bf8_t qf[2];
#pragma unroll
    for (int ks = 0; ks < 2; ++ks) {
        union { short s[8]; bf8_t v; } u;
#pragma unroll
        for (int j = 0; j < 8; ++j)
            u.s[j] = (short)query[(size_t)(b * CC + c0 + ks * 32 + lg4 * 8 + j) * HWL + m0 + li];
        qf[ks] = u.v;
    }
    // all-ones B fragment (bf16 1.0) for MFMA row-sum
    bf8_t ones;
    {
        union { short s[8]; bf8_t v; } u;
#pragma unroll
        for (int j = 0; j < 8; ++j) u.s[j] = (short)0x3F80;
        ones = u.v;
    }

    f4_t O[4];
#pragma unroll
    for (int ci = 0; ci < 4; ++ci) O[ci] = (f4_t){0.f, 0.f, 0.f, 0.f};
    float mrun[4], lrun[4];
#pragma unroll
    for (int r = 0; r < 4; ++r) { mrun[r] = -1e30f; lrun[r] = 0.f; }

    int mrow = m0 + lg4 * 4;
    float qgy  = ((mrow >> 5) + 0.5f) * 0.0625f - 1.f;
    float qgx0 = ((mrow & 31) + 0.5f) * 0.0625f - 1.f;

    for (int chunk = 0; chunk < 4; ++chunk) {
        int n0 = chunk * 64;

        // K fragments from LDS (swizzled read, 2-way free)
        bf8_t kf[4][2];
#pragma unroll
        for (int ni = 0; ni < 4; ++ni)
#pragma unroll
            for (int ks = 0; ks < 2; ++ks) {
                int addr = (ni * 16 + li) * 128 + ks * 64 + lg4 * 16;
                kf[ni][ks] = *(const bf8_t*)((const char*)KsS + (addr ^ ((li & 7) << 4)));
            }

        // T14: issue next chunk's global loads early (latency hides under compute)
        us8_t nk[2], nv[2];
        if (chunk < 3) {
            int n1 = n0 + 64;
#pragma unroll
            for (int it = 0; it < 2; ++it) {
                int Li = tid + it * 256;
                int row = Li >> 3;
                int colb = (Li & 7) * 16;
                nk[it] = *(const us8_t*)(kt  + (size_t)(b * NS + n1 + row) * CC + c0 + colb / 2);
                nv[it] = *(const us8_t*)(vst + (size_t)(b * CC + c0 + row) * NS + n1 + colb / 2);
            }
        }

        f4_t s[4];
#pragma unroll
        for (int ni = 0; ni < 4; ++ni) {
            f4_t acc = (f4_t){0.f, 0.f, 0.f, 0.f};
            acc = __builtin_amdgcn_mfma_f32_16x16x32_bf16(qf[0], kf[ni][0], acc, 0, 0, 0);
            acc = __builtin_amdgcn_mfma_f32_16x16x32_bf16(qf[1], kf[ni][1], acc, 0, 0, 0);
            s[ni] = acc;
        }

        // scale + RPE bias (C-layout: col n = li, row m = lg4*4+r)
#pragma unroll
        for (int ni = 0; ni < 4; ++ni) {
            int n = n0 + ni * 16 + li;
            float2 p2 = psl2[n];
            float gy = ((qgy - p2.x) * 0.5f + 1.f) * 15.f;
            float fy = floorf(gy);
            float wy = gy - fy;
            int iy = (int)fy;
            float gxb = (qgx0 - p2.y) * 7.5f + 15.f;   // + r*0.46875 per row
            const float2* row0 = &tabp2[(iy + 2) * 36 + 2];
#pragma unroll
            for (int r = 0; r < 4; ++r) {
                float gx = gxb + r * 0.46875f;
                float fx = floorf(gx);
                float wx = gx - fx;
                int ix = (int)fx;
                float2 t0 = row0[ix];
                float2 t1 = row0[ix + 36];
                float bias = (1.f - wy) * ((1.f - wx) * t0.x + wx * t0.y)
                           + wy * ((1.f - wx) * t1.x + wx * t1.y);
                s[ni][r] = s[ni][r] * 0.125f + bias;
            }
        }

        // online softmax: max via shuffles, SUM via MFMA-ones (below)
#pragma unroll
        for (int r = 0; r < 4; ++r) {
            float v = fmaxf(fmaxf(s[0][r], s[1][r]), fmaxf(s[2][r], s[3][r]));
            v = fmaxf(v, __shfl_xor(v, 1));
            v = fmaxf(v, __shfl_xor(v, 2));
            v = fmaxf(v, __shfl_xor(v, 4));
            v = fmaxf(v, __shfl_xor(v, 8));
            float mnew = fmaxf(mrun[r], v);
            float sc = __expf(mrun[r] - mnew);
            mrun[r] = mnew;
            lrun[r] *= sc;
#pragma unroll
            for (int ni = 0; ni < 4; ++ni)
                s[ni][r] = __expf(s[ni][r] - mnew);
#pragma unroll
            for (int ci = 0; ci < 4; ++ci) O[ci][r] *= sc;
        }
        // P -> LDS (bf16, per-wave tile; same-wave round trip, no barrier)
#pragma unroll
        for (int ni = 0; ni < 4; ++ni)
#pragma unroll
            for (int r = 0; r < 4; ++r)
                Plds[w][lg4 * 4 + r][ni * 16 + li] = f2us(s[ni][r]);

        bf8_t pf[2];
#pragma unroll
        for (int ks = 0; ks < 2; ++ks)
            pf[ks] = *(const bf8_t*)&Plds[w][li][ks * 32 + lg4 * 8];

        // row-sum of P via MFMA with ones-B: ps[r] = sum_n P[row][n]
        f4_t ps = (f4_t){0.f, 0.f, 0.f, 0.f};
        ps = __builtin_amdgcn_mfma_f32_16x16x32_bf16(pf[0], ones, ps, 0, 0, 0);
        ps = __builtin_amdgcn_mfma_f32_16x16x32_bf16(pf[1], ones, ps, 0, 0, 0);
#pragma unroll
        for (int r = 0; r < 4; ++r) lrun[r] += ps[r];

        // V fragments from LDS (swizzled), read after softmax
        bf8_t vf[4][2];
#pragma unroll
        for (int ci = 0; ci < 4; ++ci)
#pragma unroll
            for (int ks = 0; ks < 2; ++ks) {
                int addr = (ci * 16 + li) * 128 + ks * 64 + lg4 * 16;
                vf[ci][ks] = *(const bf8_t*)((const char*)VsS + (addr ^ ((li & 7) << 4)));
            }
#pragma unroll
        for (int ci = 0; ci < 4; ++ci) {
            O[ci] = __builtin_amdgcn_mfma_f32_16x16x32_bf16(pf[0], vf[ci][0], O[ci], 0, 0, 0);
            O[ci] = __builtin_amdgcn_mfma_f32_16x16x32_bf16(pf[1], vf[ci][1], O[ci], 0, 0, 0);
        }

        // rotate: publish next chunk's K/V
        if (chunk < 3) {
            __syncthreads();   // all waves done reading current K/V LDS
#pragma unroll
            for (int it = 0; it < 2; ++it) {
                int Li = tid + it * 256;
                int row = Li >> 3;
                int so = (Li * 16) ^ ((row & 7) << 4);
                *(us8_t*)((char*)KsS + so) = nk[it];
                *(us8_t*)((char*)VsS + so) = nv[it];
            }
            __syncthreads();   // staged data visible
        }
    }
    // epilogue
    float inv[4];
#pragma unroll
    for (int r = 0; r < 4; ++r) inv[r] = 1.f / lrun[r];
#pragma unroll
    for (int ci = 0; ci < 4; ++ci)
#pragma unroll
        for (int r = 0; r < 4; ++r) {
            int m = m0 + lg4 * 4 + r;
            ao[(size_t)(b * HWL + m) * CC + c0 + ci * 16 + li] = f2us(O[ci][r] * inv[r]);
        }
}

// -------------------- K5: final 1x1 projection (reg pipeline, full budget) ---
// out[b][o][m] = sum_c ao[b][m][c] * wbf[o][c]
// r18 tile (128x128, grid 768, wave 64x64). 2-deep register pipeline needs
// ~135 VGPR; r20 spilled because the DEFAULT budget assumes 1024-thr blocks
// (128-reg cap) and the allocator squeezed to the 64-reg tier (WRITE 553 MB).
// launch_bounds(256,1) declares 1 wave/EU min -> 512-reg budget, no squeeze.
// Occupancy is grid-limited (768 blk = 3/CU = 3 waves/EU) either way; the
// win is per-wave ILP: each K-step's 8 loads hide under the prior 32 MFMAs.
// Spill watch: WRITE_SIZE must stay 49 MB.
__global__ __launch_bounds__(256, 1) void k_proj(
    const u16* __restrict__ ao, const u16* __restrict__ wbf,
    float* __restrict__ out)
{
    int L = blockIdx.x;
    int xcd = L & 7;
    int t = L >> 3;            // 0..95
    int ot = t % 6;
    int gh = t / 6;            // 0..15
    int g = xcd + 8 * gh;      // 0..127 = mt + 8*b
    int mt = g & 7;
    int b = g >> 3;
    int tid = threadIdx.x;
    int w = tid >> 6, l = tid & 63;
    int li = l & 15, lg4 = l >> 4;
    int o0 = ot * 128 + (w >> 1) * 64;
    int m0 = mt * 128 + (w & 1) * 64;

    const u16* ap = ao + (size_t)b * HWL * CC;
    const u16* wp = wbf;

    f4_t acc[4][4];
#pragma unroll
    for (int i = 0; i < 4; ++i)
#pragma unroll
        for (int j = 0; j < 4; ++j) acc[i][j] = (f4_t){0.f, 0.f, 0.f, 0.f};

    // prologue: K-step 0 fragments
    bf8_t af[4][2], bfr[4][2];
#pragma unroll
    for (int i = 0; i < 4; ++i)
#pragma unroll
        for (int ks = 0; ks < 2; ++ks) {
            af[i][ks]  = *(const bf8_t*)(wp + (size_t)(o0 + i * 16 + li) * CC + ks * 32 + lg4 * 8);
            bfr[i][ks] = *(const bf8_t*)(ap + (size_t)(m0 + i * 16 + li) * CC + ks * 32 + lg4 * 8);
        }

    for (int kc = 0; kc < CC; kc += 64) {
        // issue next K-step's loads BEFORE this step's MFMAs (T14)
        bf8_t afn[4][2], bfn[4][2];
        if (kc + 64 < CC) {
            int kn = kc + 64;
#pragma unroll
            for (int i = 0; i < 4; ++i)
#pragma unroll
                for (int ks = 0; ks < 2; ++ks) {
                    afn[i][ks] = *(const bf8_t*)(wp + (size_t)(o0 + i * 16 + li) * CC + kn + ks * 32 + lg4 * 8);
                    bfn[i][ks] = *(const bf8_t*)(ap + (size_t)(m0 + i * 16 + li) * CC + kn + ks * 32 + lg4 * 8);
                }
        }
#pragma unroll
        for (int i = 0; i < 4; ++i)
#pragma unroll
            for (int j = 0; j < 4; ++j) {
                acc[i][j] = __builtin_amdgcn_mfma_f32_16x16x32_bf16(af[i][0], bfr[j][0], acc[i][j], 0, 0, 0);
                acc[i][j] = __builtin_amdgcn_mfma_f32_16x16x32_bf16(af[i][1], bfr[j][1], acc[i][j], 0, 0, 0);
            }
        if (kc + 64 < CC) {
#pragma unroll
            for (int i = 0; i < 4; ++i)
#pragma unroll
                for (int ks = 0; ks < 2; ++ks) {
                    af[i][ks]  = afn[i][ks];
                    bfr[i][ks] = bfn[i][ks];
                }
        }
    }
#pragma unroll
    for (int i = 0; i < 4; ++i)
#pragma unroll
        for (int r = 0; r < 4; ++r) {
            int o = o0 + i * 16 + lg4 * 4 + r;
            float* op = out + ((size_t)b * CC + o) * HWL + m0;
#pragma unroll
            for (int j = 0; j < 4; ++j)
                op[j * 16 + li] = acc[i][j][r];
        }
}

extern "C" void kernel_launch(void* const* d_in, const int* in_sizes, int n_in,
                              void* d_out, int out_size, void* d_ws, size_t ws_size,
                              hipStream_t stream) {
    const float* x     = (const float*)d_in[0];
    const float* wv    = (const float*)d_in[1];
    const float* bv    = (const float*)d_in[2];
    const float* wq    = (const float*)d_in[3];
    const float* bq    = (const float*)d_in[4];
    const float* wk    = (const float*)d_in[5];
    const float* bk    = (const float*)d_in[6];
    const float* wo1   = (const float*)d_in[7];
    const float* bo1   = (const float*)d_in[8];
    const float* lng   = (const float*)d_in[9];
    const float* lnb   = (const float*)d_in[10];
    const float* woff2 = (const float*)d_in[11];
    const float* rpe   = (const float*)d_in[12];
    const float* wout  = (const float*)d_in[13];
    float* out = (float*)d_out;

    char* ws = (char*)d_ws;
    size_t off = 0;
    auto alloc = [&](size_t nbytes) -> void* {
        void* p = ws + off;
        off += (nbytes + 255) & ~(size_t)255;
        return p;
    };
    u16*   value = (u16*)  alloc((size_t)BB * CC * HWL * 2);   // 25.2 MB
    u16*   query = (u16*)  alloc((size_t)BB * CC * HWL * 2);   // 25.2 MB
    u16*   key   = (u16*)  alloc((size_t)BB * CC * NS * 2);    //  6.3 MB
    float* tbuf  = (float*)alloc((size_t)BB * NS * CC * 4);    // 12.6 MB [b][c][n]
    float* pos   = (float*)alloc((size_t)BB * NS * 2 * 4);
    u16*   ao    = (u16*)  alloc((size_t)BB * HWL * CC * 2);   // 25.2 MB
    u16*   wbf   = (u16*)  alloc((size_t)CC * CC * 2);         //  1.2 MB

    // kt/vst alias tbuf (dead after k_offset): 6.3 + 6.3 = 12.6 MB exact fit
    u16* kt  = (u16*)tbuf;
    u16* vst = (u16*)((char*)tbuf + (size_t)BB * NS * CC * 2);

    k_dwconv<<<BB * CC, 256, 0, stream>>>(x, wv, bv, wq, bq, wk, bk, wo1, bo1,
                                          value, query, key, tbuf);
    k_offset<<<BB * NS, 256, 0, stream>>>(tbuf, lng, lnb, woff2, pos);
    k_sample<<<dim3(CC / 4, BB), 256, 0, stream>>>(value, pos, vst);
    k_transpose<<<dim3(NS / 64, CC / 64, BB), 256, 0, stream>>>(key, kt, CC, NS);
    k_cvtw<<<CC * CC / 1024, 256, 0, stream>>>(wout, wbf);
    k_attn<<<dim3(16 * 192), 256, 0, stream>>>(query, kt, vst, rpe, pos, ao);
    k_proj<<<dim3(768), 256, 0, stream>>>(ao, wbf, out);
}